// Round 8
// baseline (320.683 us; speedup 1.0000x reference)
//
#include <hip/hip_runtime.h>

typedef unsigned short ushort_t;
typedef unsigned int uint_t;
typedef unsigned long long u64_t;

typedef __bf16 bf16x8 __attribute__((ext_vector_type(8)));
typedef float f32x4 __attribute__((ext_vector_type(4)));

union BFU { ushort_t u; __bf16 h; };

__device__ __forceinline__ float bf2f(uint_t u) {
    union { uint_t i; float f; } v; v.i = u << 16; return v.f;
}
__device__ __forceinline__ ushort_t f2bf(float f) {
    union { float f; uint_t i; } v; v.f = f;
    uint_t r = v.i + 0x7fffu + ((v.i >> 16) & 1u);
    return (ushort_t)(r >> 16);
}
// mode: 1 = bf16 storage, 0 = fp32 storage
__device__ __forceinline__ float loadF(const void* p, size_t i, int isBf16) {
    return isBf16 ? bf2f((uint_t)((const ushort_t*)p)[i]) : ((const float*)p)[i];
}

// flags[0..10]: x,W1,b1,W2,b2,W3,b3,Wres,bres,Wlin,blin  (1=bf16, 0=fp32)
// flags[11]: edge_index is int64 (1) or int32 (0)
struct DetectArgs {
    const void* t[11];
    int elems[11];
    const int* ei;
    int* flags;
};

__device__ __forceinline__ int detect_one(const void* p, int elems) {
    const uint_t* w = (const uint_t*)p;
    int n = elems / 2; if (n > 64) n = 64;
    int cnt = 0;
    for (int k = 0; k < n; ++k) {
        uint_t f = (w[k] >> 7) & 0xFFu;
        cnt += (f >= 100u && f <= 135u);
    }
    return (cnt * 10 >= n * 6) ? 1 : 0;
}

// plane-internal position permutation: slot s (MFMA k-order) -> natural feature
// kappa(s) = 32*(s>>5) + 16*(s&1) + 4*((s>>3)&3) + ((s&7)>>1)
__device__ __forceinline__ int kappa(int s) {
    return 32 * (s >> 5) + 16 * (s & 1) + 4 * ((s >> 3) & 3) + ((s & 7) >> 1);
}

// ---------------- weight pack + dtype detection + deg zeroing ----------------
// Hbuf: planar H' buffer, 4 planes of (N+1) rows x 32 feats; zero sentinel row N of each plane.
// T2/T3/Tlin are packed with kappa() k-row permutation (A operands are pos-permuted planar).
__global__ void k_pack(DetectArgs a,
                       ushort_t* __restrict__ Tcat, ushort_t* __restrict__ T2,
                       ushort_t* __restrict__ T3, ushort_t* __restrict__ Tl,
                       int* __restrict__ deg, int N,
                       ushort_t* __restrict__ Hbuf, int hps) {
    __shared__ int lflag;
    int i = blockIdx.x * blockDim.x + threadIdx.x;
    if (i < N) deg[i] = 0;                         // fused memset
    if (blockIdx.x == 1 && threadIdx.x < 64) {     // sentinel rows (4 planes x 64 B)
        int p = threadIdx.x >> 4, w = threadIdx.x & 15;
        ((uint_t*)Hbuf)[(size_t)p * (hps / 2) + (size_t)N * 16 + w] = 0u;
    }
    const int SQ = 128 * 128;
    int m = (i < 4 * SQ) ? (i / SQ) : 4;           // uniform per block (SQ%256==0)
    int fid = (m == 0) ? 1 : (m == 1) ? 3 : (m == 2) ? 5 : (m == 3) ? 7 : 9;
    const void* W = a.t[fid];

    if (threadIdx.x == 0) lflag = detect_one(W, a.elems[fid]);
    if (blockIdx.x == 0 && threadIdx.x >= 64 && threadIdx.x < 75) {
        int t = threadIdx.x - 64;
        a.flags[t] = detect_one(a.t[t], a.elems[t]);
    }
    if (blockIdx.x == 0 && threadIdx.x == 75) {
        int nz = 0;
        for (int k = 0; k < 64; ++k) nz += (a.ei[2 * k + 1] != 0);
        a.flags[11] = (nz == 0) ? 1 : 0;
    }
    __syncthreads();
    int isb = lflag;

    if (i < 4 * SQ) {
        int r = i % SQ;
        int s = r / 128, f = r % 128;              // s = k-slot, f = output feature
        ushort_t* T = (m == 0) ? Tcat : (m == 1) ? T2 : (m == 2) ? T3 : (Tcat + SQ);
        int k = (m == 1 || m == 2) ? kappa(s) : s; // T2/T3: permuted A input
        T[f * 128 + s] = f2bf(loadF(W, (size_t)k * 128 + f, isb));
    } else if (i < 4 * SQ + 128 * 64) {
        int r = i - 4 * SQ;
        int s = r / 64, f = r % 64;
        int k = kappa(s);                          // Tlin: permuted A input
        Tl[f * 128 + s] = f2bf(loadF(W, (size_t)k * 64 + f, isb));
    }
}

// ---------------- degree + rank: the ONLY atomic pass ----------------
__global__ void k_deg(const int* __restrict__ ei, int E, int N,
                      const int* __restrict__ flags, int* __restrict__ deg,
                      int2* __restrict__ tmp) {
    int i = blockIdx.x * blockDim.x + threadIdx.x;
    int e0 = i * 4;
    if (e0 >= E) return;
    int is64 = flags[11];
    if (e0 + 3 < E && (E & 3) == 0) {
        int d[4];
        if (is64) {
            int4 va = *(const int4*)(ei + 2 * E + 2 * e0);
            int4 vb = *(const int4*)(ei + 2 * E + 2 * e0 + 4);
            d[0] = va.x; d[1] = va.z; d[2] = vb.x; d[3] = vb.z;
        } else {
            int4 va = *(const int4*)(ei + E + e0);
            d[0] = va.x; d[1] = va.y; d[2] = va.z; d[3] = va.w;
        }
        int l[4]; bool ok[4];
#pragma unroll
        for (int k = 0; k < 4; ++k) ok[k] = (unsigned)d[k] < (unsigned)N;
#pragma unroll
        for (int k = 0; k < 4; ++k)
            l[k] = ok[k] ? atomicAdd(&deg[d[k]], 1) : 0;
        int4 t01, t23;
        t01.x = ok[0] ? d[0] : -1; t01.y = l[0];
        t01.z = ok[1] ? d[1] : -1; t01.w = l[1];
        t23.x = ok[2] ? d[2] : -1; t23.y = l[2];
        t23.z = ok[3] ? d[3] : -1; t23.w = l[3];
        *(int4*)(tmp + e0) = t01;
        *(int4*)(tmp + e0 + 2) = t23;
    } else {
        for (int e = e0; e < E && e < e0 + 4; ++e) {
            int dd = is64 ? ei[2 * E + 2 * e] : ei[E + e];
            bool ok = (unsigned)dd < (unsigned)N;
            int l = ok ? atomicAdd(&deg[dd], 1) : 0;
            tmp[e] = make_int2(ok ? dd : -1, l);
        }
    }
}

// ---- scan: k_bsum (per-1024-chunk sums) + k_rowptr (self-computed offset) ----

__global__ __launch_bounds__(256) void k_bsum(const int* __restrict__ deg, int n,
                                              int* __restrict__ bsum) {
    int base = blockIdx.x * 1024;
    int local = 0;
#pragma unroll
    for (int j = 0; j < 4; ++j) {
        int idx = base + threadIdx.x + j * 256;
        if (idx < n) local += deg[idx];
    }
    __shared__ int s[4];
#pragma unroll
    for (int off = 32; off; off >>= 1) local += __shfl_down(local, off, 64);
    if ((threadIdx.x & 63) == 0) s[threadIdx.x >> 6] = local;
    __syncthreads();
    if (threadIdx.x == 0) bsum[blockIdx.x] = s[0] + s[1] + s[2] + s[3];
}

// computes own block offset by reducing bsum[0..b-1] (nb <= 64, single wave)
__global__ __launch_bounds__(256) void k_rowptr(const int* __restrict__ deg,
                                                const int* __restrict__ bsum, int n,
                                                int* __restrict__ row_ptr,
                                                float* __restrict__ dinv) {
    __shared__ int s[256];
    __shared__ int sboff;
    int t = threadIdx.x;

    if (t < 64) {
        int v = (t < blockIdx.x) ? bsum[t] : 0;   // exclusive: blocks before me
#pragma unroll
        for (int off = 32; off; off >>= 1) v += __shfl_down(v, off, 64);
        if (t == 0) sboff = v;
    }

    int base = blockIdx.x * 1024 + t * 4;
    int v0 = (base + 0 < n) ? deg[base + 0] : 0;
    int v1 = (base + 1 < n) ? deg[base + 1] : 0;
    int v2 = (base + 2 < n) ? deg[base + 2] : 0;
    int v3 = (base + 3 < n) ? deg[base + 3] : 0;
    int tot = v0 + v1 + v2 + v3;
    s[t] = tot;
    __syncthreads();
    for (int off = 1; off < 256; off <<= 1) {
        int u = (t >= off) ? s[t - off] : 0;
        __syncthreads();
        s[t] += u;
        __syncthreads();
    }
    int run = sboff + ((t == 0) ? 0 : s[t - 1]);
    int vals[4] = {v0, v1, v2, v3};
#pragma unroll
    for (int j = 0; j < 4; ++j) {
        int idx = base + j;
        if (idx < n) {
            row_ptr[idx] = run;
            run += vals[j];
            float df = (float)vals[j] + 1.0f;
            dinv[idx] = rsqrtf(df);
        }
    }
    if (blockIdx.x == gridDim.x - 1 && t == 255) row_ptr[n] = sboff + s[255];
}

// ------- scatter CSR (NO atomics): pos = row_ptr[d] + rank; col only (4B/edge) -------
__global__ void k_scatter(const int* __restrict__ ei, int E, int N,
                          const int* __restrict__ flags,
                          const int* __restrict__ row_ptr,
                          const int2* __restrict__ tmp,
                          uint_t* __restrict__ colw) {
    int i = blockIdx.x * blockDim.x + threadIdx.x;
    int e0 = i * 4;
    if (e0 >= E) return;
    int is64 = flags[11];
    if (e0 + 3 < E && (E & 3) == 0) {
        int s[4];
        if (is64) {
            int4 sa = *(const int4*)(ei + 2 * e0);
            int4 sb = *(const int4*)(ei + 2 * e0 + 4);
            s[0] = sa.x; s[1] = sa.z; s[2] = sb.x; s[3] = sb.z;
        } else {
            int4 sa = *(const int4*)(ei + e0);
            s[0] = sa.x; s[1] = sa.y; s[2] = sa.z; s[3] = sa.w;
        }
        int4 t01 = *(const int4*)(tmp + e0);
        int4 t23 = *(const int4*)(tmp + e0 + 2);
        int d[4] = {t01.x, t01.z, t23.x, t23.z};
        int l[4] = {t01.y, t01.w, t23.y, t23.w};
        int ss[4];
#pragma unroll
        for (int k = 0; k < 4; ++k)
            ss[k] = ((unsigned)s[k] < (unsigned)N) ? s[k] : 0;
#pragma unroll
        for (int k = 0; k < 4; ++k) {
            if (d[k] >= 0)
                colw[row_ptr[d[k]] + l[k]] = (uint_t)ss[k];
        }
    } else {
        for (int e = e0; e < E && e < e0 + 4; ++e) {
            int sv = is64 ? ei[2 * e] : ei[e];
            int2 tv = tmp[e];
            if (tv.x >= 0) {
                int ssv = ((unsigned)sv < (unsigned)N) ? sv : 0;
                colw[row_ptr[tv.x] + tv.y] = (uint_t)ssv;
            }
        }
    }
}

// ===== LDS-staged GEMM, 64 rows/block =====

template <int NCT>
__device__ __forceinline__ void stage_B(const ushort_t* __restrict__ WT, uint4* lds) {
    int t = threadIdx.x;
#pragma unroll
    for (int i = 0; i < NCT; ++i) {
        int g = i * 256 + t;
        uint4 v = ((const uint4*)WT)[g];
        int col = g >> 4, k8 = g & 15;
        int c = col >> 4, l16c = col & 15;
        int kk = k8 >> 2, q = k8 & 3;
        lds[((kk * NCT + c) << 6) + (q << 4) + l16c] = v;
    }
    __syncthreads();
}

// row-major A (input x), fp32 or bf16
__device__ __forceinline__ void load_A1(const void* __restrict__ A, int a16,
                                        int ar, int quad, bf16x8 af[4]) {
    if (a16) {
        const ushort_t* p = (const ushort_t*)A + (size_t)ar * 128 + quad * 8;
#pragma unroll
        for (int kk = 0; kk < 4; ++kk) af[kk] = *(const bf16x8*)(p + kk * 32);
    } else {
        const float* p = (const float*)A + (size_t)ar * 128 + quad * 8;
#pragma unroll
        for (int kk = 0; kk < 4; ++kk) {
            f32x4 u0 = *(const f32x4*)(p + kk * 32);
            f32x4 u1 = *(const f32x4*)(p + kk * 32 + 4);
#pragma unroll
            for (int j = 0; j < 4; ++j) {
                BFU e;
                e.u = f2bf(u0[j]); af[kk][j] = e.h;
                e.u = f2bf(u1[j]); af[kk][j + 4] = e.h;
            }
        }
    }
}

// planar A (4 planes of 32 feats, plane stride aps elems): af[kk] is wholly in plane kk
// (pos-permuted internal order; matched by kappa() packing of the B tile)
__device__ __forceinline__ void load_A_planar(const ushort_t* __restrict__ A, int aps,
                                              int ar, int quad, bf16x8 af[4]) {
#pragma unroll
    for (int kk = 0; kk < 4; ++kk)
        af[kk] = *(const bf16x8*)(A + (size_t)kk * aps + (size_t)ar * 32 + quad * 8);
}

// A: pos-permuted planar bf16 (stride aps). C: pos-permuted planar bf16 (cFix=1,
// paired 4B stores) or row-major fp32 (natural). rowscale folds D^-1/2.
template <int NCT>
__global__ __launch_bounds__(256, 4) void k_gemm2(const ushort_t* __restrict__ A, int aps,
                                                  const ushort_t* __restrict__ WT,
                                                  const void* __restrict__ bias, int bFid,
                                                  void* __restrict__ C, int cFix, int cps,
                                                  int M, const int* __restrict__ flags,
                                                  const float* __restrict__ rowscale) {
    __shared__ uint4 lds[NCT * 256];
    stage_B<NCT>(WT, lds);

    const int F = NCT * 16;
    int t = threadIdx.x;
    int wave = t >> 6, lane = t & 63;
    int quad = lane >> 4, l16 = lane & 15;
    int row0 = blockIdx.x * 64 + wave * 16;

    int ar = row0 + l16; if (ar >= M) ar = M - 1;

    bf16x8 af[4];
    load_A_planar(A, aps, ar, quad, af);

    f32x4 acc[NCT];
#pragma unroll
    for (int c = 0; c < NCT; ++c) acc[c] = (f32x4){0.f, 0.f, 0.f, 0.f};

#pragma unroll
    for (int kk = 0; kk < 4; ++kk) {
#pragma unroll
        for (int c = 0; c < NCT; ++c) {
            bf16x8 b = *(const bf16x8*)&lds[((kk * NCT + c) << 6) + lane];
            acc[c] = __builtin_amdgcn_mfma_f32_16x16x32_bf16(af[kk], b, acc[c], 0, 0, 0);
        }
    }

    float rs[4];
#pragma unroll
    for (int q = 0; q < 4; ++q) {
        int row = row0 + quad * 4 + q;
        rs[q] = (rowscale && row < M) ? rowscale[row] : 1.0f;
    }

    int bf = (bias && bFid >= 0) ? flags[bFid] : 1;
    if (cFix) {
        // paired 4B stores: plane p holds cols c0=2p,c1=2p+1; pos = 2*l16 + (c&1)
#pragma unroll
        for (int p = 0; p < NCT / 2; ++p) {
            int c0 = 2 * p, c1 = 2 * p + 1;
            float bv0 = bias ? loadF(bias, c0 * 16 + l16, bf) : 0.0f;
            float bv1 = bias ? loadF(bias, c1 * 16 + l16, bf) : 0.0f;
#pragma unroll
            for (int q = 0; q < 4; ++q) {
                int row = row0 + quad * 4 + q;
                if (row < M) {
                    float v0 = acc[c0][q] * rs[q] + bv0;
                    float v1 = acc[c1][q] * rs[q] + bv1;
                    uint_t u = (uint_t)f2bf(v0) | ((uint_t)f2bf(v1) << 16);
                    *(uint_t*)((ushort_t*)C + (size_t)p * cps + (size_t)row * 32 + 2 * l16) = u;
                }
            }
        }
    } else {
#pragma unroll
        for (int c = 0; c < NCT; ++c) {
            int colg = c * 16 + l16;
            float bv = bias ? loadF(bias, colg, bf) : 0.0f;
#pragma unroll
            for (int q = 0; q < 4; ++q) {
                int row = row0 + quad * 4 + q;
                if (row < M)
                    ((float*)C)[(size_t)row * F + colg] = acc[c][q] * rs[q] + bv;
            }
        }
    }
}

// layer-1 dual output, two-phase staging (32 KB LDS); Hout = acc*dinv, Xres = acc+bres,
// both pos-permuted planar with paired 4B stores. A = x (natural row-major).
__global__ __launch_bounds__(256, 4) void k_gemm_l1(const void* __restrict__ A,
                                                    const ushort_t* __restrict__ Tcat,
                                                    const void* __restrict__ bres,
                                                    ushort_t* __restrict__ Hout, int hps,
                                                    ushort_t* __restrict__ Xres, int xps,
                                                    int M, const int* __restrict__ flags,
                                                    const float* __restrict__ dinv) {
    __shared__ uint4 lds[8 * 256];
    int t = threadIdx.x;
    int wave = t >> 6, lane = t & 63;
    int quad = lane >> 4, l16 = lane & 15;
    int row0 = blockIdx.x * 64 + wave * 16;

    int a16 = flags[0];
    int ar = row0 + l16; if (ar >= M) ar = M - 1;

    bf16x8 af[4];
    load_A1(A, a16, ar, quad, af);

    float rs[4];
#pragma unroll
    for (int q = 0; q < 4; ++q) {
        int row = row0 + quad * 4 + q;
        rs[q] = (row < M) ? dinv[row] : 1.0f;
    }

    stage_B<8>(Tcat, lds);
    {
        f32x4 acc[8];
#pragma unroll
        for (int c = 0; c < 8; ++c) acc[c] = (f32x4){0.f, 0.f, 0.f, 0.f};
#pragma unroll
        for (int kk = 0; kk < 4; ++kk) {
#pragma unroll
            for (int c = 0; c < 8; ++c) {
                bf16x8 b = *(const bf16x8*)&lds[((kk * 8 + c) << 6) + lane];
                acc[c] = __builtin_amdgcn_mfma_f32_16x16x32_bf16(af[kk], b, acc[c], 0, 0, 0);
            }
        }
#pragma unroll
        for (int p = 0; p < 4; ++p) {
            int c0 = 2 * p, c1 = 2 * p + 1;
#pragma unroll
            for (int q = 0; q < 4; ++q) {
                int row = row0 + quad * 4 + q;
                if (row < M) {
                    uint_t u = (uint_t)f2bf(acc[c0][q] * rs[q]) |
                               ((uint_t)f2bf(acc[c1][q] * rs[q]) << 16);
                    *(uint_t*)(Hout + (size_t)p * hps + (size_t)row * 32 + 2 * l16) = u;
                }
            }
        }
    }
    __syncthreads();

    stage_B<8>(Tcat + 128 * 128, lds);
    {
        int bf = flags[8];
        f32x4 acc[8];
#pragma unroll
        for (int c = 0; c < 8; ++c) acc[c] = (f32x4){0.f, 0.f, 0.f, 0.f};
#pragma unroll
        for (int kk = 0; kk < 4; ++kk) {
#pragma unroll
            for (int c = 0; c < 8; ++c) {
                bf16x8 b = *(const bf16x8*)&lds[((kk * 8 + c) << 6) + lane];
                acc[c] = __builtin_amdgcn_mfma_f32_16x16x32_bf16(af[kk], b, acc[c], 0, 0, 0);
            }
        }
#pragma unroll
        for (int p = 0; p < 4; ++p) {
            int c0 = 2 * p, c1 = 2 * p + 1;
            float bv0 = loadF(bres, c0 * 16 + l16, bf);
            float bv1 = loadF(bres, c1 * 16 + l16, bf);
#pragma unroll
            for (int q = 0; q < 4; ++q) {
                int row = row0 + quad * 4 + q;
                if (row < M) {
                    uint_t u = (uint_t)f2bf(acc[c0][q] + bv0) |
                               ((uint_t)f2bf(acc[c1][q] + bv1) << 16);
                    *(uint_t*)(Xres + (size_t)p * xps + (size_t)row * 32 + 2 * l16) = u;
                }
            }
        }
    }
}

// ------- aggregation (R19): planar XCD-affine slices, 8-lane group = one node,
// uint2 gathers (8 lanes x 8 B = 64 B row; one instr = 8 edges), shfl-free
// group-uniform colw loads software-pipelined one 8-burst ahead, 32-bit offset
// addressing from uniform base. Natural bias indices derived from pos-perm. -------
__global__ __launch_bounds__(256) void k_agg(const ushort_t* __restrict__ H, int hps,
                                             const int* __restrict__ row_ptr,
                                             const uint_t* __restrict__ colw,
                                             const float* __restrict__ dinv,
                                             const void* __restrict__ bias, int bFid,
                                             const ushort_t* __restrict__ other, int ops,
                                             ushort_t* __restrict__ Out,
                                             int n, const int* __restrict__ flags) {
    int s = blockIdx.x & 3;                          // feature slice (XCD-affine)
    int wave = threadIdx.x >> 6;
    int lane = threadIdx.x & 63;
    int g8 = lane >> 3;                              // 8-lane group = one node
    int fl = lane & 7;
    int fo = fl * 4;                                 // elem offset (4 ushorts = 8 B)
    int node = (blockIdx.x >> 2) * 32 + wave * 8 + g8;
    bool ok = (node < n);
    const ushort_t* Hs = H + (size_t)s * hps;

    int nd = ok ? node : (n - 1);
    int beg = row_ptr[nd], end = row_ptr[nd + 1];
    if (!ok) end = beg;

    float a0 = 0.f, a1 = 0.f, a2 = 0.f, a3 = 0.f;

    int b = beg;
    int cq[8];
#pragma unroll
    for (int q = 0; q < 8; ++q)
        cq[q] = (b + q < end) ? (int)__builtin_nontemporal_load(&colw[b + q]) : n;
    while (b < end) {
        int bn = b + 8;
        int cn[8];
#pragma unroll
        for (int q = 0; q < 8; ++q)                  // prefetch next burst
            cn[q] = (bn + q < end) ? (int)__builtin_nontemporal_load(&colw[bn + q]) : n;
#pragma unroll
        for (int q = 0; q < 8; ++q) {
            uint_t off = (uint_t)cq[q] * 32u + (uint_t)fo;
            uint2 v = *(const uint2*)(Hs + off);
            a0 += bf2f(v.x & 0xffffu);
            a1 += bf2f(v.x >> 16);
            a2 += bf2f(v.y & 0xffffu);
            a3 += bf2f(v.y >> 16);
        }
        b = bn;
#pragma unroll
        for (int q = 0; q < 8; ++q) cq[q] = cn[q];
    }

    if (ok) {
        size_t nofs = (size_t)node * 32 + fo;
        uint2 hv = *(const uint2*)(Hs + nofs);       // self term H'[node]
        a0 += bf2f(hv.x & 0xffffu);
        a1 += bf2f(hv.x >> 16);
        a2 += bf2f(hv.y & 0xffffu);
        a3 += bf2f(hv.y >> 16);
        float dv = dinv[node];
        int bfm = flags[bFid];
        // natural features for positions 4fl..4fl+3 within plane s:
        int f0 = s * 32 + 2 * fl;                    // pos 4fl   (even)
        int f1 = s * 32 + 16 + 2 * fl;               // pos 4fl+1 (odd)
        float o0 = fmaf(a0, dv, loadF(bias, f0, bfm));
        float o1 = fmaf(a1, dv, loadF(bias, f1, bfm));
        float o2 = fmaf(a2, dv, loadF(bias, f0 + 1, bfm));
        float o3 = fmaf(a3, dv, loadF(bias, f1 + 1, bfm));
        if (other) {
            u64_t ovu = __builtin_nontemporal_load(
                (const u64_t*)(other + (size_t)s * ops + nofs));
            uint_t ovx = (uint_t)ovu, ovy = (uint_t)(ovu >> 32);
            o0 += bf2f(ovx & 0xffffu);
            o1 += bf2f(ovx >> 16);
            o2 += bf2f(ovy & 0xffffu);
            o3 += bf2f(ovy >> 16);
        }
        o0 = fmaxf(o0, 0.0f); o1 = fmaxf(o1, 0.0f);
        o2 = fmaxf(o2, 0.0f); o3 = fmaxf(o3, 0.0f);
        u64_t outv = (u64_t)((uint_t)f2bf(o0) | ((uint_t)f2bf(o1) << 16)) |
                     ((u64_t)((uint_t)f2bf(o2) | ((uint_t)f2bf(o3) << 16)) << 32);
        __builtin_nontemporal_store(outv, (u64_t*)(Out + (size_t)s * ops + nofs));
    }
}

// ---------------- launch ----------------

extern "C" void kernel_launch(void* const* d_in, const int* in_sizes, int n_in,
                              void* d_out, int out_size, void* d_ws, size_t ws_size,
                              hipStream_t stream) {
    const int N = in_sizes[0] / 128;
    const int E = in_sizes[1] / 2;

    const void* x  = d_in[0];
    const int*  ei = (const int*)d_in[1];

    char* ws = (char*)d_ws;
    size_t used = 0;
    auto alloc = [&](size_t bytes) {
        char* p = ws + used;
        used += (bytes + 255) & ~(size_t)255;
        return p;
    };

    int*   flags   = (int*)alloc(64 * 4);
    int*   deg     = (int*)alloc((size_t)N * 4);
    int*   row_ptr = (int*)alloc((size_t)(N + 1) * 4);
    float* dinv    = (float*)alloc((size_t)N * 4);
    int2*  tmp     = (int2*)alloc((size_t)E * 8);
    uint_t* colw   = (uint_t*)alloc((size_t)E * 4);
    int*   bsum    = (int*)alloc(256 * 4);
    ushort_t* Tcat = (ushort_t*)alloc(256 * 128 * 2);
    ushort_t* T2   = (ushort_t*)alloc(128 * 128 * 2);
    ushort_t* T3   = (ushort_t*)alloc(128 * 128 * 2);
    ushort_t* Tlin = (ushort_t*)alloc(128 * 64 * 2);

    ushort_t* Hbuf = (ushort_t*)alloc((size_t)(N + 1) * 128 * 2);  // 4 planes x (N+1) x 32
    ushort_t* Act1 = (ushort_t*)alloc((size_t)N * 128 * 2);        // 4 planes x N x 32
    ushort_t* Act2 = (ushort_t*)alloc((size_t)N * 128 * 2);
    ushort_t* Xres = (ushort_t*)alloc((size_t)N * 128 * 2);

    if (used > ws_size) return;

    const int PH = (N + 1) * 32;   // H plane stride (elems), has sentinel row N
    const int PA = N * 32;         // Act/Xres plane stride (elems)

    DetectArgs da;
    for (int i = 0; i < 11; ++i) { da.t[i] = d_in[i == 0 ? 0 : i + 1]; da.elems[i] = in_sizes[i == 0 ? 0 : i + 1]; }
    da.ei = ei;
    da.flags = flags;

    const int B = 256;
    int gE4   = ((E + 3) / 4 + B - 1) / B;
    int gPack = (4 * 128 * 128 + 128 * 64) / B;   // 288 blocks = 73728 threads >= N
    int gGemm = (N + 63) / 64;
    int gAgg  = ((N + 31) / 32) * 4;              // (32-node groups) x (4 slices)
    int nb    = (N + 1023) / 1024;                // 49 <= 64 (rowptr self-scan limit)

    k_pack<<<gPack, B, 0, stream>>>(da, Tcat, T2, T3, Tlin, deg, N, Hbuf, PH);
    k_deg<<<gE4, B, 0, stream>>>(ei, E, N, flags, deg, tmp);
    k_bsum<<<nb, B, 0, stream>>>(deg, N, bsum);
    k_rowptr<<<nb, B, 0, stream>>>(deg, bsum, N, row_ptr, dinv);
    k_scatter<<<gE4, B, 0, stream>>>(ei, E, N, flags, row_ptr, tmp, colw);

    // layer 1 (two-phase dual GEMM): H' = (x@W1)*dinv (planar), Xres = x@Wres + bres (planar)
    k_gemm_l1<<<gGemm, B, 0, stream>>>(x, Tcat, d_in[9], Hbuf, PH, Xres, PA, N, flags, dinv);
    k_agg<<<gAgg, B, 0, stream>>>(Hbuf, PH, row_ptr, colw, dinv, d_in[3], 2,
                                  Xres, PA, Act1, N, flags);

    // layer 2
    k_gemm2<8><<<gGemm, B, 0, stream>>>(Act1, PA, T2, nullptr, -1, Hbuf, 1, PH, N, flags, dinv);
    k_agg<<<gAgg, B, 0, stream>>>(Hbuf, PH, row_ptr, colw, dinv, d_in[5], 4,
                                  nullptr, PA, Act2, N, flags);

    // layer 3
    k_gemm2<8><<<gGemm, B, 0, stream>>>(Act2, PA, T3, nullptr, -1, Hbuf, 1, PH, N, flags, dinv);
    k_agg<<<gAgg, B, 0, stream>>>(Hbuf, PH, row_ptr, colw, dinv, d_in[7], 6,
                                  nullptr, PA, Act1, N, flags);

    // final: out = Act1@Wlin + blin (fp32 row-major out, no rowscale)
    k_gemm2<4><<<gGemm, B, 0, stream>>>(Act1, PA, Tlin, d_in[11], 10,
                                        d_out, 0, 0, N, flags, nullptr);
}